// Round 5
// baseline (3334.420 us; speedup 1.0000x reference)
//
#include <hip/hip_runtime.h>
#include <math.h>

#define NPTS 4096
#define NCH  1024
#define HH 128
#define WW 128
#define SLICE (HH*WW)
#define PARTW 2048
#define NBLK  2048

struct WsPtrs {
  double* Hg;      // 27 doubles: H upper-tri (21) then g (6)
  float* state;    // [0..8]=R,[9..11]=t,[12]=lam,[13]=prev_cost,[14..22]=R_new,[23..25]=t_new
  unsigned int* counter;
  float* p3d0;     // 3*NPTS SoA
  float* idx0x;    // NPTS (fallback path)
  float* idx0y;    // NPTS
  float* nidxx;    // NPTS (fallback)
  float* nidxy;    // NPTS (fallback)
  float* np2;      // 2*NPTS interleaved
  float* best;     // 2*NPTS interleaved
  float* P12;      // 12*NPTS (fallback)
  float* coef;     // NPTS*16 float4 (fallback)
  float* part;     // 28*PARTW per-block partials
  float* feat0;    // [NCH][NPTS]
  float* feat0t;   // [NPTS][NCH]
  float* img1t;    // [SLICE][NCH]
};

__device__ inline float w3f(int k){ return (k==1)?2.f:((k==0||k==2)?1.f:0.f); }
__device__ inline float d3f(int k){ return (k==0)?-0.125f:((k==2)?0.125f:0.f); }

// LM solve + so3exp + state update; call with single thread. Reads stot[0..27].
__device__ void lm_solve_commit(int force, WsPtrs& ws, const double* stot, int* sacc)
{
  float cost_new = (float)(stot[27] / (double)NPTS);
  int acc = force || (cost_new <= ws.state[13]);
  if (acc){
    ws.state[13]=cost_new;
    for (int k=0;k<9;k++) ws.state[k]=ws.state[14+k];
    for (int k=0;k<3;k++) ws.state[9+k]=ws.state[23+k];
    for (int a=0;a<27;a++) ws.Hg[a]=stot[a];
  }
  if (!force){
    float l = ws.state[12]*(acc?0.1f:10.f);
    ws.state[12]=fminf(fmaxf(l,1e-6f),100.f);
  }
  *sacc=acc;
  double M[6][7];
  {
    double Hf[6][6]; int p=0;
    for (int k=0;k<6;k++) for (int l=k;l<6;l++){ double v=ws.Hg[p++]; Hf[k][l]=v; Hf[l][k]=v; }
    double lam = (double)ws.state[12];
    for (int k=0;k<6;k++){
      for (int l=0;l<6;l++) M[k][l]=Hf[k][l];
      M[k][6]=ws.Hg[21+k];
    }
    for (int k=0;k<6;k++) M[k][k] = M[k][k] + (M[k][k] + 1e-9)*lam;
  }
  for (int k=0;k<6;k++){
    int pi=k; double bv=fabs(M[k][k]);
    for (int i=k+1;i<6;i++){ double v=fabs(M[i][k]); if(v>bv){bv=v;pi=i;} }
    if (pi!=k) for (int j=k;j<7;j++){ double tmp=M[k][j];M[k][j]=M[pi][j];M[pi][j]=tmp; }
    double pv=M[k][k];
    for (int i=k+1;i<6;i++){
      double f2=M[i][k]/pv;
      for (int j=k;j<7;j++) M[i][j]-=f2*M[k][j];
    }
  }
  double x[6];
  for (int k=5;k>=0;k--){
    double s=M[k][6];
    for (int j=k+1;j<6;j++) s-=M[k][j]*x[j];
    x[k]=s/M[k][k];
  }
  float dt0=(float)(-x[0]), dt1=(float)(-x[1]), dt2=(float)(-x[2]);
  float w0=(float)(-x[3]), w1=(float)(-x[4]), w2=(float)(-x[5]);
  float th2 = w0*w0+w1*w1+w2*w2;
  float th = sqrtf(fmaxf(th2, 1e-24f));
  float A_ = (th2 < 1e-16f) ? 1.f : (sinf(th)/th);
  float B_ = (th2 < 1e-16f) ? 0.5f : ((1.f - cosf(th)) / fmaxf(th2, 1e-24f));
  float Kx[9] = {0.f,-w2,w1,  w2,0.f,-w0,  -w1,w0,0.f};
  float K2[9];
  for (int i=0;i<3;i++) for (int j=0;j<3;j++){
    float s=0.f; for (int k=0;k<3;k++) s+=Kx[i*3+k]*Kx[k*3+j];
    K2[i*3+j]=s;
  }
  float dr[9];
  for (int i=0;i<9;i++) dr[i] = ((i%4==0)?1.f:0.f) + A_*Kx[i] + B_*K2[i];
  float Rn[9], tn[3];
  for (int i=0;i<3;i++) for (int j=0;j<3;j++){
    float s=0.f; for (int k=0;k<3;k++) s+=dr[i*3+k]*ws.state[k*3+j];
    Rn[i*3+j]=s;
  }
  for (int i=0;i<3;i++){
    float s=0.f; for (int k=0;k<3;k++) s+=dr[i*3+k]*ws.state[9+k];
    tn[i]=s+((i==0)?dt0:(i==1)?dt1:dt2);
  }
  for (int k=0;k<9;k++) ws.state[14+k]=Rn[k];
  for (int k=0;k<3;k++) ws.state[23+k]=tn[k];
}

// ---- init kernel: matrices + p3d0 + idx0 + counter ----
__global__ __launch_bounds__(256) void prep_init_kernel(
    const float* __restrict__ pts2d, const float* __restrict__ pts3d,
    const float* __restrict__ qm, const float* __restrict__ rm,
    const float* __restrict__ K1, WsPtrs ws)
{
  const int t = threadIdx.x;
  if (t == 0) {
    *ws.counter = 0u;
    double M[4][8];
    for (int i=0;i<4;i++) for (int j=0;j<4;j++){ M[i][j]=rm[i*4+j]; M[i][4+j]=(i==j)?1.0:0.0; }
    for (int k=0;k<4;k++){
      int p=k; double bv=fabs(M[k][k]);
      for (int i=k+1;i<4;i++){ double v=fabs(M[i][k]); if(v>bv){bv=v;p=i;} }
      if (p!=k) for (int j=0;j<8;j++){ double tmp=M[k][j]; M[k][j]=M[p][j]; M[p][j]=tmp; }
      double pv = M[k][k];
      for (int j=0;j<8;j++) M[k][j] /= pv;
      for (int i=0;i<4;i++) if (i!=k){
        double f2=M[i][k];
        for (int j=0;j<8;j++) M[i][j] -= f2*M[k][j];
      }
    }
    float rel[16];
    for (int i=0;i<4;i++) for (int j=0;j<4;j++){
      float s=0.f;
      for (int k=0;k<4;k++) s += qm[i*4+k]*(float)M[k][4+j];
      rel[i*4+j]=s;
    }
    for (int i=0;i<3;i++) for (int j=0;j<3;j++){ ws.state[i*3+j]=rel[i*4+j]; ws.state[14+i*3+j]=rel[i*4+j]; }
    for (int i=0;i<3;i++){ ws.state[9+i]=rel[i*4+3]; ws.state[23+i]=rel[i*4+3]; }
    ws.state[12] = 0.01f;
  }
  for (int i=0;i<16;i++){
    int n = t + i*256;
    float X=pts3d[n*3+0], Y=pts3d[n*3+1], Z=pts3d[n*3+2];
    float hx = rm[0]*X + rm[1]*Y + rm[2]*Z + rm[3];
    float hy = rm[4]*X + rm[5]*Y + rm[6]*Z + rm[7];
    float hz = rm[8]*X + rm[9]*Y + rm[10]*Z + rm[11];
    float hw = rm[12]*X + rm[13]*Y + rm[14]*Z + rm[15];
    ws.p3d0[n]=hx/hw; ws.p3d0[NPTS+n]=hy/hw; ws.p3d0[2*NPTS+n]=hz/hw;
    ws.idx0x[n]=pts2d[n*2+0]*0.125f;
    ws.idx0y[n]=pts2d[n*2+1]*0.125f;
  }
}

// ---- feat0 (iteration-invariant): one block per channel, writes [c][n] ----
__global__ __launch_bounds__(256) void feat0_kernel(
    const float* __restrict__ img0, const float* __restrict__ pts2d, WsPtrs ws)
{
  __shared__ __align__(16) float tile[SLICE];
  const int c = blockIdx.x;
  const int t = threadIdx.x;
  {
    const float4* g4 = reinterpret_cast<const float4*>(img0 + (size_t)c*SLICE);
    float4* t4 = reinterpret_cast<float4*>(tile);
    #pragma unroll
    for (int i=0;i<16;i++) t4[t + i*256] = g4[t + i*256];
  }
  __syncthreads();
  #pragma unroll
  for (int i=0;i<16;i++){
    int n = t + i*256;
    float x = pts2d[n*2+0]*0.125f, y = pts2d[n*2+1]*0.125f;
    float x0f=floorf(x), y0f=floorf(y);
    float wx=x-x0f, wy=y-y0f;
    int xi=min(max((int)x0f,0),WW-1);
    int yi=min(max((int)y0f,0),HH-1);
    int x1=min(xi+1,WW-1), y1=min(yi+1,HH-1);
    float f00=tile[yi*WW+xi], f10=tile[yi*WW+x1], f01=tile[y1*WW+xi], f11=tile[y1*WW+x1];
    ws.feat0[(size_t)c*NPTS + n] =
      f00*(1.f-wx)*(1.f-wy) + f10*wx*(1.f-wy) + f01*(1.f-wx)*wy + f11*wx*wy;
  }
}

// ---- generic 32x32 tiled transpose ----
__global__ __launch_bounds__(256) void transpose_kernel(
    const float* __restrict__ src, float* __restrict__ dst, int R, int Cc)
{
  __shared__ float tile[32][33];
  int bx = blockIdx.x*32, by = blockIdx.y*32;
  int tx = threadIdx.x & 31, ty = threadIdx.x >> 5;
  #pragma unroll
  for (int k=0;k<4;k++){
    int r = by + ty + k*8;
    tile[ty + k*8][tx] = src[(size_t)r*Cc + bx + tx];
  }
  __syncthreads();
  #pragma unroll
  for (int k=0;k<4;k++){
    int r = bx + ty + k*8;
    dst[(size_t)r*R + by + tx] = tile[tx][ty + k*8];
  }
}

// ---- fully-fused LM iteration: coef build + scoring + last-block commit/solve ----
__global__ __launch_bounds__(256) void iter_kernel(
    int force, const float* __restrict__ img1t, const float* __restrict__ f0t,
    const float* __restrict__ K1, WsPtrs ws, float* __restrict__ dout)
{
  __shared__ float4 scoef[2][16];
  __shared__ float sr[2][12];
  __shared__ float red6[4][6];
  __shared__ float sh6[6];
  __shared__ int slast;
  const int b = blockIdx.x, t = threadIdx.x;
  const int n0 = b*2;

  // ---- in-block coefficient build: t<32, thread -> (point pt, window pixel p)
  if (t < 32){
    const int pt = t>>4, p = t&15;
    const int n = n0 + pt;
    const float fx=K1[0], cx=K1[2], fy=K1[4], cy=K1[5];
    float sRt[12];
    #pragma unroll
    for (int k=0;k<12;k++) sRt[k]=ws.state[14+k];
    float px=ws.p3d0[n], py=ws.p3d0[NPTS+n], pz=ws.p3d0[2*NPTS+n];
    float X = sRt[0]*px + sRt[1]*py + sRt[2]*pz + sRt[9];
    float Y = sRt[3]*px + sRt[4]*py + sRt[5]*pz + sRt[10];
    float Z = sRt[6]*px + sRt[7]*py + sRt[8]*pz + sRt[11];
    float p2x = (fx*X + cx*Z)/Z;
    float p2y = (fy*Y + cy*Z)/Z;
    float xx = fminf(fmaxf(p2x*0.125f,0.f),(float)(WW-1));
    float yy = fminf(fmaxf(p2y*0.125f,0.f),(float)(HH-1));
    float a = (fx/Z)*0.125f;
    float bb = (fy/Z)*0.125f;
    float c = ((-fx*X)/Z)/Z*0.125f;
    float d = ((-fy*Y)/Z)/Z*0.125f;
    if (p == 0){
      ws.np2[2*n]=p2x; ws.np2[2*n+1]=p2y;
      sr[pt][0]=a;  sr[pt][1]=0.f; sr[pt][2]=c;  sr[pt][3]=c*Y;       sr[pt][4]=a*Z-c*X; sr[pt][5]=-a*Y;
      sr[pt][6]=0.f; sr[pt][7]=bb; sr[pt][8]=d;  sr[pt][9]=d*Y-bb*Z;  sr[pt][10]=-d*X;   sr[pt][11]=bb*X;
    }
    float x0f=floorf(xx), y0f=floorf(yy);
    float wx=xx-x0f, wy=yy-y0f;
    int xi=(int)x0f, yi=(int)y0f;
    int x1c=min(xi+1,WW-1), y1c=min(yi+1,HH-1);
    int c1 = x1c-(xi-1);
    int rr1 = y1c-(yi-1);
    float w00=(1.f-wx)*(1.f-wy), w10=wx*(1.f-wy), w01=(1.f-wx)*wy, w11=wx*wy;
    const int r = p>>2, cc = p&3;
    float a1r=w3f(r), d1r=d3f(r);
    int k2=r-rr1+1;
    float a2r=w3f(k2), d2r=d3f(k2);
    float e1r=(r==1)?1.f:0.f, e2r=(r==rr1)?1.f:0.f;
    int sy=yi-1+r;
    bool iny=(sy>=0)&&(sy<HH);
    int ay=min(max(sy,0),HH-1);
    float a1c=w3f(cc), d1c=d3f(cc);
    int k2c=cc-c1+1;
    float a2c=w3f(k2c), d2c=d3f(k2c);
    float e1c=(cc==1)?1.f:0.f, e2c=(cc==c1)?1.f:0.f;
    int sx=xi-1+cc;
    bool inb = iny && (sx>=0) && (sx<WW);
    int ax=min(max(sx,0),WW-1);
    float wf  = e1r*(w00*e1c + w10*e2c) + e2r*(w01*e1c + w11*e2c);
    float wgx = inb ? (a1r*(w00*d1c + w10*d2c) + a2r*(w01*d1c + w11*d2c)) : 0.f;
    float wgy = inb ? (d1r*(w00*a1c + w10*a2c) + d2r*(w01*a1c + w11*a2c)) : 0.f;
    float4 cf; cf.x=wf; cf.y=wgx; cf.z=wgy; cf.w=__int_as_float(ay*WW+ax);
    scoef[pt][p]=cf;
  }
  int kk=0, ll=0;
  if (t < 21){ int rem=t, k=0; while (rem >= 6-k){ rem -= 6-k; k++; } kk=k; ll=k+rem; }
  __syncthreads();

  // ---- scoring: 2 points, 4 channels (float4) per thread
  float part28 = 0.f;
  const float* ip = img1t + 4*t;
  #pragma unroll
  for (int pt=0; pt<2; pt++){
    const int n = n0 + pt;
    float f10=0.f,f11=0.f,f12=0.f,f13=0.f;
    float gx0=0.f,gx1=0.f,gx2=0.f,gx3=0.f;
    float gy0=0.f,gy1=0.f,gy2=0.f,gy3=0.f;
    #pragma unroll
    for (int p=0;p<16;p++){
      float4 cf = scoef[pt][p];
      int pix = __float_as_int(cf.w);
      float4 v = *(const float4*)(ip + ((size_t)pix<<10));
      f10 = fmaf(cf.x, v.x, f10); f11 = fmaf(cf.x, v.y, f11);
      f12 = fmaf(cf.x, v.z, f12); f13 = fmaf(cf.x, v.w, f13);
      gx0 = fmaf(cf.y, v.x, gx0); gx1 = fmaf(cf.y, v.y, gx1);
      gx2 = fmaf(cf.y, v.z, gx2); gx3 = fmaf(cf.y, v.w, gx3);
      gy0 = fmaf(cf.z, v.x, gy0); gy1 = fmaf(cf.z, v.y, gy1);
      gy2 = fmaf(cf.z, v.z, gy2); gy3 = fmaf(cf.z, v.w, gy3);
    }
    float4 f0 = *(const float4*)(f0t + ((size_t)n<<10) + 4*t);
    float e0=f10-f0.x, e1=f11-f0.y, e2=f12-f0.z, e3=f13-f0.w;
    float v6[6];
    v6[0] = gx0*gx0 + gx1*gx1 + gx2*gx2 + gx3*gx3;
    v6[1] = gx0*gy0 + gx1*gy1 + gx2*gy2 + gx3*gy3;
    v6[2] = gy0*gy0 + gy1*gy1 + gy2*gy2 + gy3*gy3;
    v6[3] = e0*gx0 + e1*gx1 + e2*gx2 + e3*gx3;
    v6[4] = e0*gy0 + e1*gy1 + e2*gy2 + e3*gy3;
    v6[5] = e0*e0 + e1*e1 + e2*e2 + e3*e3;
    #pragma unroll
    for (int j=0;j<6;j++){
      float vv=v6[j];
      for (int off=32; off>0; off>>=1) vv += __shfl_down(vv, off, 64);
      v6[j]=vv;
    }
    int wave=t>>6, lane=t&63;
    if (lane==0){
      #pragma unroll
      for (int j=0;j<6;j++) red6[wave][j]=v6[j];
    }
    __syncthreads();
    if (t<6) sh6[t] = red6[0][t]+red6[1][t]+red6[2][t]+red6[3][t];
    __syncthreads();
    if (t<28){
      float m0=sh6[0], m1=sh6[1], m2=sh6[2], s0=sh6[3], s1=sh6[4], ss=sh6[5];
      const float* r0 = sr[pt];
      const float* r1 = sr[pt]+6;
      float ev;
      if (t<21)      ev = m0*r0[kk]*r0[ll] + m1*(r0[kk]*r1[ll] + r1[kk]*r0[ll]) + m2*r1[kk]*r1[ll];
      else if (t<27) ev = s0*r0[t-21] + s1*r1[t-21];
      else           ev = ss;
      part28 += ev;
    }
    __syncthreads();
  }
  if (t<28) ws.part[(size_t)t*PARTW + b] = part28;

  // ---- last-block commit + solve + best/out
  __threadfence();
  __syncthreads();
  if (t==0){
    unsigned int old = atomicAdd(ws.counter, 1u);
    slast = (old == (unsigned int)(gridDim.x - 1)) ? 1 : 0;
  }
  __syncthreads();
  if (!slast) return;
  __threadfence();  // acquire: make other blocks' part/np2 writes visible

  __shared__ float red[4*28];
  __shared__ double stot[28];
  __shared__ int sacc;
  float loc[28];
  #pragma unroll
  for (int a=0;a<28;a++){
    const float* pa = ws.part + (size_t)a*PARTW;
    float s=0.f;
    #pragma unroll
    for (int k=0;k<8;k++) s += pa[t + k*256];
    loc[a]=s;
  }
  #pragma unroll
  for (int a=0;a<28;a++){
    float vv=loc[a];
    for (int off=32;off>0;off>>=1) vv += __shfl_down(vv,off,64);
    loc[a]=vv;
  }
  int wave=t>>6, lane=t&63;
  if (lane==0){
    #pragma unroll
    for (int a=0;a<28;a++) red[wave*28+a]=loc[a];
  }
  __syncthreads();
  if (t<28) stot[t] = (double)red[t]+(double)red[28+t]+(double)red[56+t]+(double)red[84+t];
  __syncthreads();
  if (t==0){
    lm_solve_commit(force, ws, stot, &sacc);
    atomicExch(ws.counter, 0u);   // reset for next launch
  }
  __syncthreads();
  int acc=sacc;
  float2* best2=(float2*)ws.best;
  const float2* np22=(const float2*)ws.np2;
  float2* out2=(float2*)dout;
  #pragma unroll
  for (int i=0;i<16;i++){
    int n=t+i*256;
    if (acc) best2[n]=np22[n];
    out2[n]=best2[n];
  }
}

// ======== fallback path (ws too small): round-4 proven kernels ========

__global__ __launch_bounds__(256) void build_kernel(const float* __restrict__ K1, WsPtrs ws)
{
  const int n = blockIdx.x*256 + threadIdx.x;
  const float fx=K1[0], cx=K1[2], fy=K1[4], cy=K1[5];
  float sRt[12];
  #pragma unroll
  for (int k=0;k<12;k++) sRt[k]=ws.state[14+k];
  float px=ws.p3d0[n], py=ws.p3d0[NPTS+n], pz=ws.p3d0[2*NPTS+n];
  float X = sRt[0]*px + sRt[1]*py + sRt[2]*pz + sRt[9];
  float Y = sRt[3]*px + sRt[4]*py + sRt[5]*pz + sRt[10];
  float Z = sRt[6]*px + sRt[7]*py + sRt[8]*pz + sRt[11];
  float p2x = (fx*X + cx*Z)/Z;
  float p2y = (fy*Y + cy*Z)/Z;
  ws.np2[2*n]=p2x; ws.np2[2*n+1]=p2y;
  float xx = fminf(fmaxf(p2x*0.125f,0.f),(float)(WW-1));
  float yy = fminf(fmaxf(p2y*0.125f,0.f),(float)(HH-1));
  ws.nidxx[n]=xx; ws.nidxy[n]=yy;
  float a = (fx/Z)*0.125f;
  float b = (fy/Z)*0.125f;
  float c = ((-fx*X)/Z)/Z*0.125f;
  float d = ((-fy*Y)/Z)/Z*0.125f;
  float r0[6] = {a, 0.f, c, c*Y, a*Z - c*X, -a*Y};
  float r1[6] = {0.f, b, d, d*Y - b*Z, -d*X, b*X};
  #pragma unroll
  for (int k=0;k<6;k++){ ws.P12[n*12+k]=r0[k]; ws.P12[n*12+6+k]=r1[k]; }
}

__global__ __launch_bounds__(256) void bigfb_kernel(
    const float* __restrict__ img0, const float* __restrict__ img1, WsPtrs ws)
{
  __shared__ __align__(16) float tile[SLICE];
  const int c = blockIdx.x;
  const int t = threadIdx.x;
  {
    const float4* g4 = reinterpret_cast<const float4*>(img1 + (size_t)c*SLICE);
    float4* t4 = reinterpret_cast<float4*>(tile);
    #pragma unroll
    for (int i=0;i<16;i++) t4[t + i*256] = g4[t + i*256];
  }
  __syncthreads();
  float f1a[16], gxa[16], gya[16];
  #pragma unroll
  for (int i=0;i<16;i++){
    int n = t + i*256;
    float x = ws.nidxx[n], y = ws.nidxy[n];
    float x0f = floorf(x), y0f = floorf(y);
    float wx = x - x0f, wy = y - y0f;
    int xi = (int)x0f, yi = (int)y0f;
    float v[4][4];
    if (xi>=1 && xi<=WW-3 && yi>=1 && yi<=HH-3) {
      int base = (yi-1)*WW + (xi-1);
      #pragma unroll
      for (int r=0;r<4;r++)
        #pragma unroll
        for (int cc=0;cc<4;cc++)
          v[r][cc] = tile[base + r*WW + cc];
    } else {
      #pragma unroll
      for (int r=0;r<4;r++){
        int ry = yi-1+r;
        bool okr = (ry>=0) && (ry<HH);
        int ryc = min(max(ry,0),HH-1);
        #pragma unroll
        for (int cc=0;cc<4;cc++){
          int rx = xi-1+cc;
          bool ok = okr && (rx>=0) && (rx<WW);
          int rxc = min(max(rx,0),WW-1);
          float val = tile[ryc*WW + rxc];
          v[r][cc] = ok ? val : 0.f;
        }
      }
    }
    float D1[4], D2[4], E0a[4], E1a[4];
    #pragma unroll
    for (int r=0;r<4;r++){ D1[r]=v[r][2]-v[r][0]; D2[r]=v[r][3]-v[r][1]; }
    #pragma unroll
    for (int cc=0;cc<4;cc++){ E0a[cc]=v[2][cc]-v[0][cc]; E1a[cc]=v[3][cc]-v[1][cc]; }
    float gx00 = D1[0] + 2.f*D1[1] + D1[2];
    float gx01 = D2[0] + 2.f*D2[1] + D2[2];
    float gx10 = D1[1] + 2.f*D1[2] + D1[3];
    float gx11 = D2[1] + 2.f*D2[2] + D2[3];
    float gy00 = E0a[0] + 2.f*E0a[1] + E0a[2];
    float gy01 = E0a[1] + 2.f*E0a[2] + E0a[3];
    float gy10 = E1a[0] + 2.f*E1a[1] + E1a[2];
    float gy11 = E1a[1] + 2.f*E1a[2] + E1a[3];
    float w00=(1.f-wx)*(1.f-wy), w10=wx*(1.f-wy), w01=(1.f-wx)*wy, w11=wx*wy;
    f1a[i] = w00*v[1][1] + w10*v[1][2] + w01*v[2][1] + w11*v[2][2];
    gxa[i] = 0.125f*(w00*gx00 + w10*gx01 + w01*gx10 + w11*gx11);
    gya[i] = 0.125f*(w00*gy00 + w10*gy01 + w01*gy10 + w11*gy11);
  }
  __syncthreads();
  {
    const float4* g4 = reinterpret_cast<const float4*>(img0 + (size_t)c*SLICE);
    float4* t4 = reinterpret_cast<float4*>(tile);
    #pragma unroll
    for (int i=0;i<16;i++) t4[t + i*256] = g4[t + i*256];
  }
  __syncthreads();
  float acc[28];
  #pragma unroll
  for (int a=0;a<28;a++) acc[a]=0.f;
  for (int i=0;i<16;i++){
    int n = t + i*256;
    float x = ws.idx0x[n], y = ws.idx0y[n];
    float x0f=floorf(x), y0f=floorf(y);
    float wx=x-x0f, wy=y-y0f;
    int xi=min(max((int)x0f,0),WW-1);
    int yi=min(max((int)y0f,0),HH-1);
    int x1=min(xi+1,WW-1), y1=min(yi+1,HH-1);
    float f00=tile[yi*WW+xi], f10=tile[yi*WW+x1], f01=tile[y1*WW+xi], f11=tile[y1*WW+x1];
    float feat0 = f00*(1.f-wx)*(1.f-wy) + f10*wx*(1.f-wy) + f01*(1.f-wx)*wy + f11*wx*wy;
    float e = f1a[i] - feat0;
    float gx = gxa[i], gy = gya[i];
    const float* r0 = ws.P12 + (size_t)n*12;
    const float* r1 = r0 + 6;
    float jv[6];
    #pragma unroll
    for (int k=0;k<6;k++) jv[k] = gx*r0[k] + gy*r1[k];
    int p=0;
    #pragma unroll
    for (int k=0;k<6;k++)
      #pragma unroll
      for (int l=k;l<6;l++)
        { acc[p] += jv[k]*jv[l]; p++; }
    #pragma unroll
    for (int k=0;k<6;k++) acc[21+k] += e*jv[k];
    acc[27] += e*e;
  }
  __syncthreads();
  #pragma unroll
  for (int a=0;a<28;a++){
    float vv=acc[a];
    for (int off=32; off>0; off>>=1) vv += __shfl_down(vv, off, 64);
    acc[a]=vv;
  }
  int wave = t>>6, lane = t&63;
  if (lane==0){
    #pragma unroll
    for (int a=0;a<28;a++) tile[wave*28+a]=acc[a];
  }
  __syncthreads();
  if (t<28){
    float s = tile[t]+tile[28+t]+tile[56+t]+tile[84+t];
    ws.part[(size_t)t*PARTW + c] = s;
    ws.part[(size_t)t*PARTW + 1024 + c] = 0.f;
  }
}

__global__ __launch_bounds__(256) void solve_kernel(
    int force, WsPtrs ws, float* __restrict__ dout)
{
  const int t = threadIdx.x;
  __shared__ float red[4*28];
  __shared__ double stot[28];
  __shared__ int sacc;
  float loc[28];
  #pragma unroll
  for (int a=0;a<28;a++){
    const float* pa = ws.part + (size_t)a*PARTW;
    float s=0.f;
    #pragma unroll
    for (int k=0;k<8;k++) s += pa[t + k*256];
    loc[a]=s;
  }
  #pragma unroll
  for (int a=0;a<28;a++){
    float vv=loc[a];
    for (int off=32;off>0;off>>=1) vv += __shfl_down(vv,off,64);
    loc[a]=vv;
  }
  int wave=t>>6, lane=t&63;
  if (lane==0){
    #pragma unroll
    for (int a=0;a<28;a++) red[wave*28+a]=loc[a];
  }
  __syncthreads();
  if (t<28) stot[t] = (double)red[t]+(double)red[28+t]+(double)red[56+t]+(double)red[84+t];
  __syncthreads();
  if (t==0) lm_solve_commit(force, ws, stot, &sacc);
  __syncthreads();
  int acc=sacc;
  float2* best2=(float2*)ws.best;
  const float2* np22=(const float2*)ws.np2;
  float2* out2=(float2*)dout;
  #pragma unroll
  for (int i=0;i<16;i++){
    int n=t+i*256;
    if (acc) best2[n]=np22[n];
    out2[n]=best2[n];
  }
}

extern "C" void kernel_launch(void* const* d_in, const int* in_sizes, int n_in,
                              void* d_out, int out_size, void* d_ws, size_t ws_size,
                              hipStream_t stream) {
  (void)in_sizes; (void)n_in; (void)out_size;
  const float* img0  = (const float*)d_in[0];
  const float* img1  = (const float*)d_in[1];
  const float* pts2d = (const float*)d_in[2];
  const float* pts3d = (const float*)d_in[3];
  const float* qm    = (const float*)d_in[4];
  const float* rm    = (const float*)d_in[5];
  const float* K1    = (const float*)d_in[6];
  float* out = (float*)d_out;

  char* w = (char*)d_ws;
  WsPtrs ws;
  ws.Hg      = (double*)w;
  ws.state   = (float*)(w + 256);
  ws.counter = (unsigned int*)(w + 384);
  float* f = (float*)(w + 512);
  ws.p3d0  = f; f += 3*NPTS;
  ws.idx0x = f; f += NPTS;
  ws.idx0y = f; f += NPTS;
  ws.nidxx = f; f += NPTS;
  ws.nidxy = f; f += NPTS;
  ws.np2   = f; f += 2*NPTS;
  ws.best  = f; f += 2*NPTS;
  ws.P12   = f; f += 12*NPTS;
  ws.coef  = f; f += 64*NPTS;
  ws.part  = f; f += 28*PARTW;
  ws.feat0  = f; f += (size_t)NCH*NPTS;
  ws.feat0t = f; f += (size_t)NCH*NPTS;
  ws.img1t  = f; f += (size_t)NCH*SLICE;
  size_t need = ((char*)f) - w;
  bool fast = (ws_size >= need);

  prep_init_kernel<<<1,256,0,stream>>>(pts2d, pts3d, qm, rm, K1, ws);
  if (fast) {
    feat0_kernel<<<NCH,256,0,stream>>>(img0, pts2d, ws);
    transpose_kernel<<<dim3(NPTS/32, NCH/32),256,0,stream>>>(ws.feat0, ws.feat0t, NCH, NPTS);
    transpose_kernel<<<dim3(SLICE/32, NCH/32),256,0,stream>>>(img1, ws.img1t, NCH, SLICE);
    iter_kernel<<<NBLK,256,0,stream>>>(1, ws.img1t, ws.feat0t, K1, ws, out);
    for (int it=0; it<10; ++it)
      iter_kernel<<<NBLK,256,0,stream>>>(0, ws.img1t, ws.feat0t, K1, ws, out);
  } else {
    build_kernel<<<NPTS/256,256,0,stream>>>(K1, ws);
    bigfb_kernel<<<NCH,256,0,stream>>>(img0, img1, ws);
    solve_kernel<<<1,256,0,stream>>>(1, ws, out);
    for (int it=0; it<10; ++it){
      build_kernel<<<NPTS/256,256,0,stream>>>(K1, ws);
      bigfb_kernel<<<NCH,256,0,stream>>>(img0, img1, ws);
      solve_kernel<<<1,256,0,stream>>>(0, ws, out);
    }
  }
}

// Round 6
// 769.621 us; speedup vs baseline: 4.3325x; 4.3325x over previous
//
#include <hip/hip_runtime.h>
#include <math.h>

#define NPTS 4096
#define NCH  1024
#define HH 128
#define WW 128
#define SLICE (HH*WW)
#define PARTW 2048
#define NBLK  2048

struct WsPtrs {
  double* Hg;      // 27 doubles: H upper-tri (21) then g (6)
  float* state;    // [0..8]=R,[9..11]=t,[12]=lam,[13]=prev_cost,[14..22]=R_new,[23..25]=t_new
  float* p3d0;     // 3*NPTS SoA
  float* idx0x;    // NPTS (fallback path)
  float* idx0y;    // NPTS
  float* nidxx;    // NPTS (fallback)
  float* nidxy;    // NPTS (fallback)
  float* np2;      // 2*NPTS interleaved
  float* best;     // 2*NPTS interleaved
  float* P12;      // 12*NPTS (fallback)
  float* part;     // 28*PARTW per-block partials
  float* feat0;    // [NCH][NPTS]
  float* feat0t;   // [NPTS][NCH]
  float* img1t;    // [SLICE][NCH]
};

__device__ inline float w3f(int k){ return (k==1)?2.f:((k==0||k==2)?1.f:0.f); }
__device__ inline float d3f(int k){ return (k==0)?-0.125f:((k==2)?0.125f:0.f); }

// LM solve + so3exp + state update; call with single thread. Reads stot[0..27].
__device__ void lm_solve_commit(int force, WsPtrs& ws, const double* stot, int* sacc)
{
  float cost_new = (float)(stot[27] / (double)NPTS);
  int acc = force || (cost_new <= ws.state[13]);
  if (acc){
    ws.state[13]=cost_new;
    for (int k=0;k<9;k++) ws.state[k]=ws.state[14+k];
    for (int k=0;k<3;k++) ws.state[9+k]=ws.state[23+k];
    for (int a=0;a<27;a++) ws.Hg[a]=stot[a];
  }
  if (!force){
    float l = ws.state[12]*(acc?0.1f:10.f);
    ws.state[12]=fminf(fmaxf(l,1e-6f),100.f);
  }
  *sacc=acc;
  double M[6][7];
  {
    double Hf[6][6]; int p=0;
    for (int k=0;k<6;k++) for (int l=k;l<6;l++){ double v=ws.Hg[p++]; Hf[k][l]=v; Hf[l][k]=v; }
    double lam = (double)ws.state[12];
    for (int k=0;k<6;k++){
      for (int l=0;l<6;l++) M[k][l]=Hf[k][l];
      M[k][6]=ws.Hg[21+k];
    }
    for (int k=0;k<6;k++) M[k][k] = M[k][k] + (M[k][k] + 1e-9)*lam;
  }
  for (int k=0;k<6;k++){
    int pi=k; double bv=fabs(M[k][k]);
    for (int i=k+1;i<6;i++){ double v=fabs(M[i][k]); if(v>bv){bv=v;pi=i;} }
    if (pi!=k) for (int j=k;j<7;j++){ double tmp=M[k][j];M[k][j]=M[pi][j];M[pi][j]=tmp; }
    double pv=M[k][k];
    for (int i=k+1;i<6;i++){
      double f2=M[i][k]/pv;
      for (int j=k;j<7;j++) M[i][j]-=f2*M[k][j];
    }
  }
  double x[6];
  for (int k=5;k>=0;k--){
    double s=M[k][6];
    for (int j=k+1;j<6;j++) s-=M[k][j]*x[j];
    x[k]=s/M[k][k];
  }
  float dt0=(float)(-x[0]), dt1=(float)(-x[1]), dt2=(float)(-x[2]);
  float w0=(float)(-x[3]), w1=(float)(-x[4]), w2=(float)(-x[5]);
  float th2 = w0*w0+w1*w1+w2*w2;
  float th = sqrtf(fmaxf(th2, 1e-24f));
  float A_ = (th2 < 1e-16f) ? 1.f : (sinf(th)/th);
  float B_ = (th2 < 1e-16f) ? 0.5f : ((1.f - cosf(th)) / fmaxf(th2, 1e-24f));
  float Kx[9] = {0.f,-w2,w1,  w2,0.f,-w0,  -w1,w0,0.f};
  float K2[9];
  for (int i=0;i<3;i++) for (int j=0;j<3;j++){
    float s=0.f; for (int k=0;k<3;k++) s+=Kx[i*3+k]*Kx[k*3+j];
    K2[i*3+j]=s;
  }
  float dr[9];
  for (int i=0;i<9;i++) dr[i] = ((i%4==0)?1.f:0.f) + A_*Kx[i] + B_*K2[i];
  float Rn[9], tn[3];
  for (int i=0;i<3;i++) for (int j=0;j<3;j++){
    float s=0.f; for (int k=0;k<3;k++) s+=dr[i*3+k]*ws.state[k*3+j];
    Rn[i*3+j]=s;
  }
  for (int i=0;i<3;i++){
    float s=0.f; for (int k=0;k<3;k++) s+=dr[i*3+k]*ws.state[9+k];
    tn[i]=s+((i==0)?dt0:(i==1)?dt1:dt2);
  }
  for (int k=0;k<9;k++) ws.state[14+k]=Rn[k];
  for (int k=0;k<3;k++) ws.state[23+k]=tn[k];
}

// ---- init kernel: matrices + p3d0 + idx0 ----
__global__ __launch_bounds__(256) void prep_init_kernel(
    const float* __restrict__ pts2d, const float* __restrict__ pts3d,
    const float* __restrict__ qm, const float* __restrict__ rm,
    const float* __restrict__ K1, WsPtrs ws)
{
  const int t = threadIdx.x;
  if (t == 0) {
    double M[4][8];
    for (int i=0;i<4;i++) for (int j=0;j<4;j++){ M[i][j]=rm[i*4+j]; M[i][4+j]=(i==j)?1.0:0.0; }
    for (int k=0;k<4;k++){
      int p=k; double bv=fabs(M[k][k]);
      for (int i=k+1;i<4;i++){ double v=fabs(M[i][k]); if(v>bv){bv=v;p=i;} }
      if (p!=k) for (int j=0;j<8;j++){ double tmp=M[k][j]; M[k][j]=M[p][j]; M[p][j]=tmp; }
      double pv = M[k][k];
      for (int j=0;j<8;j++) M[k][j] /= pv;
      for (int i=0;i<4;i++) if (i!=k){
        double f2=M[i][k];
        for (int j=0;j<8;j++) M[i][j] -= f2*M[k][j];
      }
    }
    float rel[16];
    for (int i=0;i<4;i++) for (int j=0;j<4;j++){
      float s=0.f;
      for (int k=0;k<4;k++) s += qm[i*4+k]*(float)M[k][4+j];
      rel[i*4+j]=s;
    }
    for (int i=0;i<3;i++) for (int j=0;j<3;j++){ ws.state[i*3+j]=rel[i*4+j]; ws.state[14+i*3+j]=rel[i*4+j]; }
    for (int i=0;i<3;i++){ ws.state[9+i]=rel[i*4+3]; ws.state[23+i]=rel[i*4+3]; }
    ws.state[12] = 0.01f;
  }
  for (int i=0;i<16;i++){
    int n = t + i*256;
    float X=pts3d[n*3+0], Y=pts3d[n*3+1], Z=pts3d[n*3+2];
    float hx = rm[0]*X + rm[1]*Y + rm[2]*Z + rm[3];
    float hy = rm[4]*X + rm[5]*Y + rm[6]*Z + rm[7];
    float hz = rm[8]*X + rm[9]*Y + rm[10]*Z + rm[11];
    float hw = rm[12]*X + rm[13]*Y + rm[14]*Z + rm[15];
    ws.p3d0[n]=hx/hw; ws.p3d0[NPTS+n]=hy/hw; ws.p3d0[2*NPTS+n]=hz/hw;
    ws.idx0x[n]=pts2d[n*2+0]*0.125f;
    ws.idx0y[n]=pts2d[n*2+1]*0.125f;
  }
}

// ---- feat0 (iteration-invariant): one block per channel, writes [c][n] ----
__global__ __launch_bounds__(256) void feat0_kernel(
    const float* __restrict__ img0, const float* __restrict__ pts2d, WsPtrs ws)
{
  __shared__ __align__(16) float tile[SLICE];
  const int c = blockIdx.x;
  const int t = threadIdx.x;
  {
    const float4* g4 = reinterpret_cast<const float4*>(img0 + (size_t)c*SLICE);
    float4* t4 = reinterpret_cast<float4*>(tile);
    #pragma unroll
    for (int i=0;i<16;i++) t4[t + i*256] = g4[t + i*256];
  }
  __syncthreads();
  #pragma unroll
  for (int i=0;i<16;i++){
    int n = t + i*256;
    float x = pts2d[n*2+0]*0.125f, y = pts2d[n*2+1]*0.125f;
    float x0f=floorf(x), y0f=floorf(y);
    float wx=x-x0f, wy=y-y0f;
    int xi=min(max((int)x0f,0),WW-1);
    int yi=min(max((int)y0f,0),HH-1);
    int x1=min(xi+1,WW-1), y1=min(yi+1,HH-1);
    float f00=tile[yi*WW+xi], f10=tile[yi*WW+x1], f01=tile[y1*WW+xi], f11=tile[y1*WW+x1];
    ws.feat0[(size_t)c*NPTS + n] =
      f00*(1.f-wx)*(1.f-wy) + f10*wx*(1.f-wy) + f01*(1.f-wx)*wy + f11*wx*wy;
  }
}

// ---- generic 32x32 tiled transpose ----
__global__ __launch_bounds__(256) void transpose_kernel(
    const float* __restrict__ src, float* __restrict__ dst, int R, int Cc)
{
  __shared__ float tile[32][33];
  int bx = blockIdx.x*32, by = blockIdx.y*32;
  int tx = threadIdx.x & 31, ty = threadIdx.x >> 5;
  #pragma unroll
  for (int k=0;k<4;k++){
    int r = by + ty + k*8;
    tile[ty + k*8][tx] = src[(size_t)r*Cc + bx + tx];
  }
  __syncthreads();
  #pragma unroll
  for (int k=0;k<4;k++){
    int r = bx + ty + k*8;
    dst[(size_t)r*R + by + tx] = tile[tx][ty + k*8];
  }
}

// ---- per-iteration scoring: in-block coef build + streaming gather; NO fences ----
__global__ __launch_bounds__(256) void iter_score_kernel(
    const float* __restrict__ img1t, const float* __restrict__ f0t,
    const float* __restrict__ K1, WsPtrs ws)
{
  __shared__ float4 scoef[2][16];
  __shared__ float sr[2][12];
  __shared__ float red6[4][6];
  __shared__ float sh6[6];
  const int b = blockIdx.x, t = threadIdx.x;
  const int n0 = b*2;

  // in-block coefficient build: t<32, thread -> (point pt, window pixel p)
  if (t < 32){
    const int pt = t>>4, p = t&15;
    const int n = n0 + pt;
    const float fx=K1[0], cx=K1[2], fy=K1[4], cy=K1[5];
    float sRt[12];
    #pragma unroll
    for (int k=0;k<12;k++) sRt[k]=ws.state[14+k];
    float px=ws.p3d0[n], py=ws.p3d0[NPTS+n], pz=ws.p3d0[2*NPTS+n];
    float X = sRt[0]*px + sRt[1]*py + sRt[2]*pz + sRt[9];
    float Y = sRt[3]*px + sRt[4]*py + sRt[5]*pz + sRt[10];
    float Z = sRt[6]*px + sRt[7]*py + sRt[8]*pz + sRt[11];
    float p2x = (fx*X + cx*Z)/Z;
    float p2y = (fy*Y + cy*Z)/Z;
    float xx = fminf(fmaxf(p2x*0.125f,0.f),(float)(WW-1));
    float yy = fminf(fmaxf(p2y*0.125f,0.f),(float)(HH-1));
    float a = (fx/Z)*0.125f;
    float bb = (fy/Z)*0.125f;
    float c = ((-fx*X)/Z)/Z*0.125f;
    float d = ((-fy*Y)/Z)/Z*0.125f;
    if (p == 0){
      ws.np2[2*n]=p2x; ws.np2[2*n+1]=p2y;
      sr[pt][0]=a;  sr[pt][1]=0.f; sr[pt][2]=c;  sr[pt][3]=c*Y;       sr[pt][4]=a*Z-c*X; sr[pt][5]=-a*Y;
      sr[pt][6]=0.f; sr[pt][7]=bb; sr[pt][8]=d;  sr[pt][9]=d*Y-bb*Z;  sr[pt][10]=-d*X;   sr[pt][11]=bb*X;
    }
    float x0f=floorf(xx), y0f=floorf(yy);
    float wx=xx-x0f, wy=yy-y0f;
    int xi=(int)x0f, yi=(int)y0f;
    int x1c=min(xi+1,WW-1), y1c=min(yi+1,HH-1);
    int c1 = x1c-(xi-1);
    int rr1 = y1c-(yi-1);
    float w00=(1.f-wx)*(1.f-wy), w10=wx*(1.f-wy), w01=(1.f-wx)*wy, w11=wx*wy;
    const int r = p>>2, cc = p&3;
    float a1r=w3f(r), d1r=d3f(r);
    int k2=r-rr1+1;
    float a2r=w3f(k2), d2r=d3f(k2);
    float e1r=(r==1)?1.f:0.f, e2r=(r==rr1)?1.f:0.f;
    int sy=yi-1+r;
    bool iny=(sy>=0)&&(sy<HH);
    int ay=min(max(sy,0),HH-1);
    float a1c=w3f(cc), d1c=d3f(cc);
    int k2c=cc-c1+1;
    float a2c=w3f(k2c), d2c=d3f(k2c);
    float e1c=(cc==1)?1.f:0.f, e2c=(cc==c1)?1.f:0.f;
    int sx=xi-1+cc;
    bool inb = iny && (sx>=0) && (sx<WW);
    int ax=min(max(sx,0),WW-1);
    float wf  = e1r*(w00*e1c + w10*e2c) + e2r*(w01*e1c + w11*e2c);
    float wgx = inb ? (a1r*(w00*d1c + w10*d2c) + a2r*(w01*d1c + w11*d2c)) : 0.f;
    float wgy = inb ? (d1r*(w00*a1c + w10*a2c) + d2r*(w01*a1c + w11*a2c)) : 0.f;
    float4 cf; cf.x=wf; cf.y=wgx; cf.z=wgy; cf.w=__int_as_float(ay*WW+ax);
    scoef[pt][p]=cf;
  }
  int kk=0, ll=0;
  if (t < 21){ int rem=t, k=0; while (rem >= 6-k){ rem -= 6-k; k++; } kk=k; ll=k+rem; }
  __syncthreads();

  // scoring: 2 points, 4 channels (float4) per thread
  float part28 = 0.f;
  const float* ip = img1t + 4*t;
  #pragma unroll
  for (int pt=0; pt<2; pt++){
    float f10=0.f,f11=0.f,f12=0.f,f13=0.f;
    float gx0=0.f,gx1=0.f,gx2=0.f,gx3=0.f;
    float gy0=0.f,gy1=0.f,gy2=0.f,gy3=0.f;
    #pragma unroll
    for (int p=0;p<16;p++){
      float4 cf = scoef[pt][p];
      int pix = __float_as_int(cf.w);
      float4 v = *(const float4*)(ip + ((size_t)pix<<10));
      f10 = fmaf(cf.x, v.x, f10); f11 = fmaf(cf.x, v.y, f11);
      f12 = fmaf(cf.x, v.z, f12); f13 = fmaf(cf.x, v.w, f13);
      gx0 = fmaf(cf.y, v.x, gx0); gx1 = fmaf(cf.y, v.y, gx1);
      gx2 = fmaf(cf.y, v.z, gx2); gx3 = fmaf(cf.y, v.w, gx3);
      gy0 = fmaf(cf.z, v.x, gy0); gy1 = fmaf(cf.z, v.y, gy1);
      gy2 = fmaf(cf.z, v.z, gy2); gy3 = fmaf(cf.z, v.w, gy3);
    }
    float4 f0 = *(const float4*)(f0t + ((size_t)(n0+pt)<<10) + 4*t);
    float e0=f10-f0.x, e1=f11-f0.y, e2=f12-f0.z, e3=f13-f0.w;
    float v6[6];
    v6[0] = gx0*gx0 + gx1*gx1 + gx2*gx2 + gx3*gx3;
    v6[1] = gx0*gy0 + gx1*gy1 + gx2*gy2 + gx3*gy3;
    v6[2] = gy0*gy0 + gy1*gy1 + gy2*gy2 + gy3*gy3;
    v6[3] = e0*gx0 + e1*gx1 + e2*gx2 + e3*gx3;
    v6[4] = e0*gy0 + e1*gy1 + e2*gy2 + e3*gy3;
    v6[5] = e0*e0 + e1*e1 + e2*e2 + e3*e3;
    #pragma unroll
    for (int j=0;j<6;j++){
      float vv=v6[j];
      for (int off=32; off>0; off>>=1) vv += __shfl_down(vv, off, 64);
      v6[j]=vv;
    }
    int wave=t>>6, lane=t&63;
    if (lane==0){
      #pragma unroll
      for (int j=0;j<6;j++) red6[wave][j]=v6[j];
    }
    __syncthreads();
    if (t<6) sh6[t] = red6[0][t]+red6[1][t]+red6[2][t]+red6[3][t];
    __syncthreads();
    if (t<28){
      float m0=sh6[0], m1=sh6[1], m2=sh6[2], s0=sh6[3], s1=sh6[4], ss=sh6[5];
      const float* r0 = sr[pt];
      const float* r1 = sr[pt]+6;
      float ev;
      if (t<21)      ev = m0*r0[kk]*r0[ll] + m1*(r0[kk]*r1[ll] + r1[kk]*r0[ll]) + m2*r1[kk]*r1[ll];
      else if (t<27) ev = s0*r0[t-21] + s1*r1[t-21];
      else           ev = ss;
      part28 += ev;
    }
    __syncthreads();
  }
  if (t<28) ws.part[(size_t)t*PARTW + b] = part28;
}

// ---- commit + LM solve + best/out (single block) ----
__global__ __launch_bounds__(256) void solve_kernel(
    int force, WsPtrs ws, float* __restrict__ dout)
{
  const int t = threadIdx.x;
  __shared__ float red[4*28];
  __shared__ double stot[28];
  __shared__ int sacc;
  float loc[28];
  #pragma unroll
  for (int a=0;a<28;a++){
    const float* pa = ws.part + (size_t)a*PARTW;
    float s=0.f;
    #pragma unroll
    for (int k=0;k<8;k++) s += pa[t + k*256];
    loc[a]=s;
  }
  #pragma unroll
  for (int a=0;a<28;a++){
    float vv=loc[a];
    for (int off=32;off>0;off>>=1) vv += __shfl_down(vv,off,64);
    loc[a]=vv;
  }
  int wave=t>>6, lane=t&63;
  if (lane==0){
    #pragma unroll
    for (int a=0;a<28;a++) red[wave*28+a]=loc[a];
  }
  __syncthreads();
  if (t<28) stot[t] = (double)red[t]+(double)red[28+t]+(double)red[56+t]+(double)red[84+t];
  __syncthreads();
  if (t==0) lm_solve_commit(force, ws, stot, &sacc);
  __syncthreads();
  int acc=sacc;
  float2* best2=(float2*)ws.best;
  const float2* np22=(const float2*)ws.np2;
  float2* out2=(float2*)dout;
  #pragma unroll
  for (int i=0;i<16;i++){
    int n=t+i*256;
    if (acc) best2[n]=np22[n];
    out2[n]=best2[n];
  }
}

// ======== fallback path (ws too small): round-4 proven kernels ========

__global__ __launch_bounds__(256) void build_kernel(const float* __restrict__ K1, WsPtrs ws)
{
  const int n = blockIdx.x*256 + threadIdx.x;
  const float fx=K1[0], cx=K1[2], fy=K1[4], cy=K1[5];
  float sRt[12];
  #pragma unroll
  for (int k=0;k<12;k++) sRt[k]=ws.state[14+k];
  float px=ws.p3d0[n], py=ws.p3d0[NPTS+n], pz=ws.p3d0[2*NPTS+n];
  float X = sRt[0]*px + sRt[1]*py + sRt[2]*pz + sRt[9];
  float Y = sRt[3]*px + sRt[4]*py + sRt[5]*pz + sRt[10];
  float Z = sRt[6]*px + sRt[7]*py + sRt[8]*pz + sRt[11];
  float p2x = (fx*X + cx*Z)/Z;
  float p2y = (fy*Y + cy*Z)/Z;
  ws.np2[2*n]=p2x; ws.np2[2*n+1]=p2y;
  float xx = fminf(fmaxf(p2x*0.125f,0.f),(float)(WW-1));
  float yy = fminf(fmaxf(p2y*0.125f,0.f),(float)(HH-1));
  ws.nidxx[n]=xx; ws.nidxy[n]=yy;
  float a = (fx/Z)*0.125f;
  float b = (fy/Z)*0.125f;
  float c = ((-fx*X)/Z)/Z*0.125f;
  float d = ((-fy*Y)/Z)/Z*0.125f;
  float r0[6] = {a, 0.f, c, c*Y, a*Z - c*X, -a*Y};
  float r1[6] = {0.f, b, d, d*Y - b*Z, -d*X, b*X};
  #pragma unroll
  for (int k=0;k<6;k++){ ws.P12[n*12+k]=r0[k]; ws.P12[n*12+6+k]=r1[k]; }
}

__global__ __launch_bounds__(256) void bigfb_kernel(
    const float* __restrict__ img0, const float* __restrict__ img1, WsPtrs ws)
{
  __shared__ __align__(16) float tile[SLICE];
  const int c = blockIdx.x;
  const int t = threadIdx.x;
  {
    const float4* g4 = reinterpret_cast<const float4*>(img1 + (size_t)c*SLICE);
    float4* t4 = reinterpret_cast<float4*>(tile);
    #pragma unroll
    for (int i=0;i<16;i++) t4[t + i*256] = g4[t + i*256];
  }
  __syncthreads();
  float f1a[16], gxa[16], gya[16];
  #pragma unroll
  for (int i=0;i<16;i++){
    int n = t + i*256;
    float x = ws.nidxx[n], y = ws.nidxy[n];
    float x0f = floorf(x), y0f = floorf(y);
    float wx = x - x0f, wy = y - y0f;
    int xi = (int)x0f, yi = (int)y0f;
    float v[4][4];
    if (xi>=1 && xi<=WW-3 && yi>=1 && yi<=HH-3) {
      int base = (yi-1)*WW + (xi-1);
      #pragma unroll
      for (int r=0;r<4;r++)
        #pragma unroll
        for (int cc=0;cc<4;cc++)
          v[r][cc] = tile[base + r*WW + cc];
    } else {
      #pragma unroll
      for (int r=0;r<4;r++){
        int ry = yi-1+r;
        bool okr = (ry>=0) && (ry<HH);
        int ryc = min(max(ry,0),HH-1);
        #pragma unroll
        for (int cc=0;cc<4;cc++){
          int rx = xi-1+cc;
          bool ok = okr && (rx>=0) && (rx<WW);
          int rxc = min(max(rx,0),WW-1);
          float val = tile[ryc*WW + rxc];
          v[r][cc] = ok ? val : 0.f;
        }
      }
    }
    float D1[4], D2[4], E0a[4], E1a[4];
    #pragma unroll
    for (int r=0;r<4;r++){ D1[r]=v[r][2]-v[r][0]; D2[r]=v[r][3]-v[r][1]; }
    #pragma unroll
    for (int cc=0;cc<4;cc++){ E0a[cc]=v[2][cc]-v[0][cc]; E1a[cc]=v[3][cc]-v[1][cc]; }
    float gx00 = D1[0] + 2.f*D1[1] + D1[2];
    float gx01 = D2[0] + 2.f*D2[1] + D2[2];
    float gx10 = D1[1] + 2.f*D1[2] + D1[3];
    float gx11 = D2[1] + 2.f*D2[2] + D2[3];
    float gy00 = E0a[0] + 2.f*E0a[1] + E0a[2];
    float gy01 = E0a[1] + 2.f*E0a[2] + E0a[3];
    float gy10 = E1a[0] + 2.f*E1a[1] + E1a[2];
    float gy11 = E1a[1] + 2.f*E1a[2] + E1a[3];
    float w00=(1.f-wx)*(1.f-wy), w10=wx*(1.f-wy), w01=(1.f-wx)*wy, w11=wx*wy;
    f1a[i] = w00*v[1][1] + w10*v[1][2] + w01*v[2][1] + w11*v[2][2];
    gxa[i] = 0.125f*(w00*gx00 + w10*gx01 + w01*gx10 + w11*gx11);
    gya[i] = 0.125f*(w00*gy00 + w10*gy01 + w01*gy10 + w11*gy11);
  }
  __syncthreads();
  {
    const float4* g4 = reinterpret_cast<const float4*>(img0 + (size_t)c*SLICE);
    float4* t4 = reinterpret_cast<float4*>(tile);
    #pragma unroll
    for (int i=0;i<16;i++) t4[t + i*256] = g4[t + i*256];
  }
  __syncthreads();
  float acc[28];
  #pragma unroll
  for (int a=0;a<28;a++) acc[a]=0.f;
  for (int i=0;i<16;i++){
    int n = t + i*256;
    float x = ws.idx0x[n], y = ws.idx0y[n];
    float x0f=floorf(x), y0f=floorf(y);
    float wx=x-x0f, wy=y-y0f;
    int xi=min(max((int)x0f,0),WW-1);
    int yi=min(max((int)y0f,0),HH-1);
    int x1=min(xi+1,WW-1), y1=min(yi+1,HH-1);
    float f00=tile[yi*WW+xi], f10=tile[yi*WW+x1], f01=tile[y1*WW+xi], f11=tile[y1*WW+x1];
    float feat0 = f00*(1.f-wx)*(1.f-wy) + f10*wx*(1.f-wy) + f01*(1.f-wx)*wy + f11*wx*wy;
    float e = f1a[i] - feat0;
    float gx = gxa[i], gy = gya[i];
    const float* r0 = ws.P12 + (size_t)n*12;
    const float* r1 = r0 + 6;
    float jv[6];
    #pragma unroll
    for (int k=0;k<6;k++) jv[k] = gx*r0[k] + gy*r1[k];
    int p=0;
    #pragma unroll
    for (int k=0;k<6;k++)
      #pragma unroll
      for (int l=k;l<6;l++)
        { acc[p] += jv[k]*jv[l]; p++; }
    #pragma unroll
    for (int k=0;k<6;k++) acc[21+k] += e*jv[k];
    acc[27] += e*e;
  }
  __syncthreads();
  #pragma unroll
  for (int a=0;a<28;a++){
    float vv=acc[a];
    for (int off=32; off>0; off>>=1) vv += __shfl_down(vv, off, 64);
    acc[a]=vv;
  }
  int wave = t>>6, lane = t&63;
  if (lane==0){
    #pragma unroll
    for (int a=0;a<28;a++) tile[wave*28+a]=acc[a];
  }
  __syncthreads();
  if (t<28){
    float s = tile[t]+tile[28+t]+tile[56+t]+tile[84+t];
    ws.part[(size_t)t*PARTW + c] = s;
    ws.part[(size_t)t*PARTW + 1024 + c] = 0.f;
  }
}

extern "C" void kernel_launch(void* const* d_in, const int* in_sizes, int n_in,
                              void* d_out, int out_size, void* d_ws, size_t ws_size,
                              hipStream_t stream) {
  (void)in_sizes; (void)n_in; (void)out_size;
  const float* img0  = (const float*)d_in[0];
  const float* img1  = (const float*)d_in[1];
  const float* pts2d = (const float*)d_in[2];
  const float* pts3d = (const float*)d_in[3];
  const float* qm    = (const float*)d_in[4];
  const float* rm    = (const float*)d_in[5];
  const float* K1    = (const float*)d_in[6];
  float* out = (float*)d_out;

  char* w = (char*)d_ws;
  WsPtrs ws;
  ws.Hg      = (double*)w;
  ws.state   = (float*)(w + 256);
  float* f = (float*)(w + 512);
  ws.p3d0  = f; f += 3*NPTS;
  ws.idx0x = f; f += NPTS;
  ws.idx0y = f; f += NPTS;
  ws.nidxx = f; f += NPTS;
  ws.nidxy = f; f += NPTS;
  ws.np2   = f; f += 2*NPTS;
  ws.best  = f; f += 2*NPTS;
  ws.P12   = f; f += 12*NPTS;
  ws.part  = f; f += 28*PARTW;
  ws.feat0  = f; f += (size_t)NCH*NPTS;
  ws.feat0t = f; f += (size_t)NCH*NPTS;
  ws.img1t  = f; f += (size_t)NCH*SLICE;
  size_t need = ((char*)f) - w;
  bool fast = (ws_size >= need);

  prep_init_kernel<<<1,256,0,stream>>>(pts2d, pts3d, qm, rm, K1, ws);
  if (fast) {
    feat0_kernel<<<NCH,256,0,stream>>>(img0, pts2d, ws);
    transpose_kernel<<<dim3(NPTS/32, NCH/32),256,0,stream>>>(ws.feat0, ws.feat0t, NCH, NPTS);
    transpose_kernel<<<dim3(SLICE/32, NCH/32),256,0,stream>>>(img1, ws.img1t, NCH, SLICE);
    iter_score_kernel<<<NBLK,256,0,stream>>>(ws.img1t, ws.feat0t, K1, ws);
    solve_kernel<<<1,256,0,stream>>>(1, ws, out);
    for (int it=0; it<10; ++it){
      iter_score_kernel<<<NBLK,256,0,stream>>>(ws.img1t, ws.feat0t, K1, ws);
      solve_kernel<<<1,256,0,stream>>>(0, ws, out);
    }
  } else {
    build_kernel<<<NPTS/256,256,0,stream>>>(K1, ws);
    bigfb_kernel<<<NCH,256,0,stream>>>(img0, img1, ws);
    solve_kernel<<<1,256,0,stream>>>(1, ws, out);
    for (int it=0; it<10; ++it){
      build_kernel<<<NPTS/256,256,0,stream>>>(K1, ws);
      bigfb_kernel<<<NCH,256,0,stream>>>(img0, img1, ws);
      solve_kernel<<<1,256,0,stream>>>(0, ws, out);
    }
  }
}